// Round 3
// baseline (454.541 us; speedup 1.0000x reference)
//
#include <hip/hip_runtime.h>
#include <hip/hip_bf16.h>

// PFNN: out[n][b] = L3(tanh(L2(tanh(L1(tanh(L0(x)))))))  B=4, H=32, D_IN=3,
// N=1048576.  f16 MFMA 16x16x32 computing out^T = W^T h^T per 16-pt subtile.
// R2 changes vs R1 (which showed occupancy-independent 117us => saturated
// trans/VALU issue):
//  - tanh = copysign(2r-1, y),  r = 1/(1+exp2(-|y|)) with exp2 via HW
//    v_exp_f32 (neg-abs input mods free) and r via PACKED-f16 Newton
//    (seed 24/17 - 8/17*d on d in [1,2], 2 NR).  1 trans + ~5 pk ops per
//    PAIR of values vs 2 trans + 2 full per value before.
//  - L3 (32->1) via MFMA with W3 in A row 0; bpermute gather; ONE float4
//    store per point (R1 wrote 104MB HBM for a 16.8MB output: partial-line RMW).
// Weights/biases of L0..L2 pre-scaled by 2*log2(e) so y is in exp2 domain.

#define NPTS 1048576
constexpr int GRID_BLOCKS = 1024;
constexpr int BLOCK_THREADS = 512;           // 8 waves
constexpr float TANH_SCALE = 2.885390081777927f;  // 2*log2(e)

typedef _Float16 h8v __attribute__((ext_vector_type(8)));
typedef _Float16 h2v __attribute__((ext_vector_type(2)));
typedef float f4v __attribute__((ext_vector_type(4)));

union H8 { h8v h; int i[4]; };

__device__ __forceinline__ float fexp2(float x) {
#if __has_builtin(__builtin_amdgcn_exp2f)
  return __builtin_amdgcn_exp2f(x);
#else
  float r;
  asm("v_exp_f32 %0, %1" : "=v"(r) : "v"(x));
  return r;
#endif
}

__device__ __forceinline__ int pkrtz(float a, float b) {
  return __builtin_bit_cast(int, __builtin_amdgcn_cvt_pkrtz(a, b));
}

// Packed tanh of 2 values. pe = f16x2{exp2(-|y0|), exp2(-|y1|)}, ps carries
// the sign bits of (y0,y1).  r = 1/(1+e') via f16 Newton; tanh|y| = 2r-1 >= 0;
// then insert sign bits (bfi pattern).
__device__ __forceinline__ int tanh2(int pe, int ps) {
  h2v e = __builtin_bit_cast(h2v, pe);
  h2v d = e + (_Float16)1.0f;                      // d in [1,2]
  h2v r = d * (_Float16)(-8.0f / 17.0f) + (_Float16)(24.0f / 17.0f);
  r = r * ((_Float16)2.0f - d * r);                // NR1: err 5.9% -> 0.35%
  r = r * ((_Float16)2.0f - d * r);                // NR2: -> f16 rounding
  h2v g = r * (_Float16)2.0f - (_Float16)1.0f;     // tanh(|y|) in [0,1)
  int gi = __builtin_bit_cast(int, g);
  return (ps & 0x80008000) | (gi & 0x7fff7fff);    // copysign (v_bfi)
}

// tanh both accumulator tiles (8 f32 values), pack, redistribute into the
// next layer's B-fragment via 8 ds_bpermute + tile select.
__device__ __forceinline__ H8 make_bfrag(f4v a0, f4v a1, int addrA, int addrB,
                                         bool tsel) {
  float e00 = fexp2(-__builtin_fabsf(a0[0])), e01 = fexp2(-__builtin_fabsf(a0[1]));
  float e02 = fexp2(-__builtin_fabsf(a0[2])), e03 = fexp2(-__builtin_fabsf(a0[3]));
  float e10 = fexp2(-__builtin_fabsf(a1[0])), e11 = fexp2(-__builtin_fabsf(a1[1]));
  float e12 = fexp2(-__builtin_fabsf(a1[2])), e13 = fexp2(-__builtin_fabsf(a1[3]));
  int pk00 = tanh2(pkrtz(e00, e01), pkrtz(a0[0], a0[1]));  // tile0 units (4g,4g+1)
  int pk01 = tanh2(pkrtz(e02, e03), pkrtz(a0[2], a0[3]));  // tile0 units (4g+2,4g+3)
  int pk10 = tanh2(pkrtz(e10, e11), pkrtz(a1[0], a1[1]));  // tile1
  int pk11 = tanh2(pkrtz(e12, e13), pkrtz(a1[2], a1[3]));
  int r0a = __builtin_amdgcn_ds_bpermute(addrA, pk00);
  int r0b = __builtin_amdgcn_ds_bpermute(addrA, pk10);
  int r1a = __builtin_amdgcn_ds_bpermute(addrA, pk01);
  int r1b = __builtin_amdgcn_ds_bpermute(addrA, pk11);
  int r2a = __builtin_amdgcn_ds_bpermute(addrB, pk00);
  int r2b = __builtin_amdgcn_ds_bpermute(addrB, pk10);
  int r3a = __builtin_amdgcn_ds_bpermute(addrB, pk01);
  int r3b = __builtin_amdgcn_ds_bpermute(addrB, pk11);
  H8 hf;
  hf.i[0] = tsel ? r0b : r0a;
  hf.i[1] = tsel ? r1b : r1a;
  hf.i[2] = tsel ? r2b : r2a;
  hf.i[3] = tsel ? r3b : r3a;
  return hf;
}

extern "C" __global__ void __launch_bounds__(BLOCK_THREADS, 8) pfnn_kernel(
    const float* __restrict__ X,
    const float* __restrict__ W0, const float* __restrict__ B0,
    const float* __restrict__ W1, const float* __restrict__ B1,
    const float* __restrict__ W2, const float* __restrict__ B2,
    const float* __restrict__ W3, const float* __restrict__ B3,
    float* __restrict__ Out) {
  __shared__ alignas(16) _Float16 lWT0[4][32][4];    // [b][u][k] k<3: s*W0, k==3: s*b0
  __shared__ alignas(16) _Float16 lWT1[4][32][40];   // [b][u][k], rows padded to 80B
  __shared__ alignas(16) _Float16 lWT2[4][32][40];
  __shared__ alignas(16) float lB1[4][32];           // s*b1 (MFMA C operand)
  __shared__ alignas(16) float lB2[4][32];
  __shared__ alignas(16) _Float16 lW3h[4][32];       // RAW W3 (L3 has no tanh)
  __shared__ float lb3[4];

  const int tid = threadIdx.x;
  for (int idx = tid; idx < 512; idx += BLOCK_THREADS) {
    int b = idx >> 7, u = (idx >> 2) & 31, k = idx & 3;
    float v = (k < 3) ? W0[(b * 3 + k) * 32 + u] : B0[b * 32 + u];
    lWT0[b][u][k] = (_Float16)(v * TANH_SCALE);
  }
  for (int idx = tid; idx < 4096; idx += BLOCK_THREADS) {
    int b = idx >> 10, k = (idx >> 5) & 31, u = idx & 31;
    lWT1[b][u][k] = (_Float16)(W1[idx] * TANH_SCALE);
    lWT2[b][u][k] = (_Float16)(W2[idx] * TANH_SCALE);
  }
  for (int idx = tid; idx < 128; idx += BLOCK_THREADS) {
    int b = idx >> 5, u = idx & 31;
    lB1[b][u] = B1[idx] * TANH_SCALE;
    lB2[b][u] = B2[idx] * TANH_SCALE;
    lW3h[b][u] = (_Float16)W3[idx];
  }
  if (tid < 4) lb3[tid] = B3[tid];
  __syncthreads();

  const int lane = tid & 63;
  const int wv = tid >> 6;       // 0..7
  const int g = lane >> 4;       // k-group
  const int p = lane & 15;       // point within subtile
  const bool g0 = (g == 0);
  const bool tsel = (g >= 2);
  const int addrA = (((g & 1) << 5) | p) << 2;  // src lane 32*(g&1)+p
  const int addrB = addrA + 64;                  // src lane +16
  const int addrP = p << 2;                      // gather: src lane p

  const int nblk = NPTS >> 6;    // 64 points per wave-iteration
  for (int blk = blockIdx.x * 8 + wv; blk < nblk; blk += GRID_BLOCKS * 8) {
    const int base = blk << 6;
    const float* xp = X + (size_t)(base + lane) * 3;
    float x0 = xp[0], x1 = xp[1], x2 = xp[2];

    // Branch-independent x B-fragments for the 4 subtiles (k<3: x, k==3: 1.0).
    H8 xf[4];
#pragma unroll
    for (int s = 0; s < 4; ++s) {
      int a = (16 * s + p) << 2;
      float fx0 = __int_as_float(__builtin_amdgcn_ds_bpermute(a, __float_as_int(x0)));
      float fx1 = __int_as_float(__builtin_amdgcn_ds_bpermute(a, __float_as_int(x1)));
      float fx2 = __int_as_float(__builtin_amdgcn_ds_bpermute(a, __float_as_int(x2)));
      int q0 = pkrtz(fx0, fx1);
      int q1 = pkrtz(fx2, 1.0f);
      xf[s].i[0] = g0 ? q0 : 0;
      xf[s].i[1] = g0 ? q1 : 0;
      xf[s].i[2] = 0;
      xf[s].i[3] = 0;
    }

    f4v res4;
#pragma unroll
    for (int b = 0; b < 4; ++b) {
      // Hoisted per-branch weight fragments.
      H8 w0a[2];
      h8v w1a[2], w2a[2];
      f4v bs1[2], bs2[2];
#pragma unroll
      for (int t = 0; t < 2; ++t) {
        const int* q = (const int*)&lWT0[b][16 * t + p][0];
        int q0 = q[0], q1 = q[1];
        w0a[t].i[0] = g0 ? q0 : 0;
        w0a[t].i[1] = g0 ? q1 : 0;
        w0a[t].i[2] = 0;
        w0a[t].i[3] = 0;
        w1a[t] = *(const h8v*)&lWT1[b][16 * t + p][8 * g];
        w2a[t] = *(const h8v*)&lWT2[b][16 * t + p][8 * g];
        bs1[t] = *(const f4v*)&lB1[b][16 * t + 4 * g];
        bs2[t] = *(const f4v*)&lB2[b][16 * t + 4 * g];
      }
      // L3 A-fragment: W3^T padded into row 0 (lanes with p==0 hold w3[8g..]).
      h8v w3z = {0, 0, 0, 0, 0, 0, 0, 0};
      h8v w3a = (p == 0) ? *(const h8v*)&lW3h[b][8 * g] : w3z;
      float b3s = lb3[b];
      float os[4];

#pragma unroll
      for (int s = 0; s < 4; ++s) {
        f4v z = {0.f, 0.f, 0.f, 0.f};
        // L0 (bias folded in k==3 row of W0')
        f4v a0 = __builtin_amdgcn_mfma_f32_16x16x32_f16(w0a[0].h, xf[s].h, z, 0, 0, 0);
        f4v a1 = __builtin_amdgcn_mfma_f32_16x16x32_f16(w0a[1].h, xf[s].h, z, 0, 0, 0);
        H8 hf = make_bfrag(a0, a1, addrA, addrB, tsel);
        // L1
        a0 = __builtin_amdgcn_mfma_f32_16x16x32_f16(w1a[0], hf.h, bs1[0], 0, 0, 0);
        a1 = __builtin_amdgcn_mfma_f32_16x16x32_f16(w1a[1], hf.h, bs1[1], 0, 0, 0);
        hf = make_bfrag(a0, a1, addrA, addrB, tsel);
        // L2
        a0 = __builtin_amdgcn_mfma_f32_16x16x32_f16(w2a[0], hf.h, bs2[0], 0, 0, 0);
        a1 = __builtin_amdgcn_mfma_f32_16x16x32_f16(w2a[1], hf.h, bs2[1], 0, 0, 0);
        hf = make_bfrag(a0, a1, addrA, addrB, tsel);
        // L3: one MFMA; row 0 (lanes 0..15, reg 0) = out[point p]
        f4v o = __builtin_amdgcn_mfma_f32_16x16x32_f16(w3a, hf.h, z, 0, 0, 0);
        os[s] = o[0];
      }
      // Gather: lane l=16g+p needs subtile g's value for point p (in lane p).
      float r0 = __int_as_float(__builtin_amdgcn_ds_bpermute(addrP, __float_as_int(os[0])));
      float r1 = __int_as_float(__builtin_amdgcn_ds_bpermute(addrP, __float_as_int(os[1])));
      float r2 = __int_as_float(__builtin_amdgcn_ds_bpermute(addrP, __float_as_int(os[2])));
      float r3 = __int_as_float(__builtin_amdgcn_ds_bpermute(addrP, __float_as_int(os[3])));
      float rr = (g == 0) ? r0 : (g == 1) ? r1 : (g == 2) ? r2 : r3;
      res4[b] = rr + b3s;
    }
    *(f4v*)(Out + (size_t)(base + lane) * 4) = res4;   // one 16B store/point
  }
}

extern "C" void kernel_launch(void* const* d_in, const int* in_sizes, int n_in,
                              void* d_out, int out_size, void* d_ws, size_t ws_size,
                              hipStream_t stream) {
  (void)in_sizes; (void)n_in; (void)out_size; (void)d_ws; (void)ws_size;
  const float* X  = (const float*)d_in[0];
  const float* W0 = (const float*)d_in[1];
  const float* B0 = (const float*)d_in[2];
  const float* W1 = (const float*)d_in[3];
  const float* B1 = (const float*)d_in[4];
  const float* W2 = (const float*)d_in[5];
  const float* B2 = (const float*)d_in[6];
  const float* W3 = (const float*)d_in[7];
  const float* B3 = (const float*)d_in[8];
  float* Out = (float*)d_out;
  pfnn_kernel<<<dim3(GRID_BLOCKS), dim3(BLOCK_THREADS), 0, stream>>>(
      X, W0, B0, W1, B1, W2, B2, W3, B3, Out);
}

// Round 4
// 231.672 us; speedup vs baseline: 1.9620x; 1.9620x over previous
//
#include <hip/hip_runtime.h>
#include <hip/hip_bf16.h>

// PFNN: out[n][b] = L3(tanh(L2(tanh(L1(tanh(L0(x)))))))  B=4, H=32, D_IN=3,
// N=1048576.  f16 MFMA 16x16x32 computing out^T = W^T h^T per 16-pt subtile.
// R3 changes vs R2 (which spilled: launch_bounds(512,8) forced VGPR<=64,
// 1.2GB scratch traffic, 390us):
//  - __launch_bounds__(512, 4): VGPR cap 128, live set ~90 -> no spill.
//    (R0/R1 proved occupancy past ~30% doesn't help; issue-saturated.)
//  - bfrag redistribution via permlane32_swap + permlane16_swap (full-rate
//    VALU, 4 instrs) instead of 8 ds_bpermute + 4 cndmask.  Derivation:
//    quadrant Qi holds tile0 (A0,A1) / tile1 (B0,B1) packed pairs;
//    w0=[A0Q0,A0Q2,B0Q0,B0Q2] = swap16(swap32(A0,B0)); w2 = other output.
//  - tanh = copysign(2r-1, y), r = 1/(1+exp2(-|y|)): 1 trans (v_exp_f32,
//    neg-abs mods free) + packed-f16 Newton (seed 24/17-8/17*d, 2 NR).
// Weights/biases of L0..L2 pre-scaled by 2*log2(e) so y is in exp2 domain.

#define NPTS 1048576
constexpr int GRID_BLOCKS = 1024;
constexpr int BLOCK_THREADS = 512;           // 8 waves
constexpr float TANH_SCALE = 2.885390081777927f;  // 2*log2(e)

typedef _Float16 h8v __attribute__((ext_vector_type(8)));
typedef _Float16 h2v __attribute__((ext_vector_type(2)));
typedef float f4v __attribute__((ext_vector_type(4)));
typedef unsigned int u2v __attribute__((ext_vector_type(2)));

union H8 { h8v h; int i[4]; };

__device__ __forceinline__ float fexp2(float x) {
#if __has_builtin(__builtin_amdgcn_exp2f)
  return __builtin_amdgcn_exp2f(x);
#else
  float r;
  asm("v_exp_f32 %0, %1" : "=v"(r) : "v"(x));
  return r;
#endif
}

__device__ __forceinline__ int pkrtz(float a, float b) {
  return __builtin_bit_cast(int, __builtin_amdgcn_cvt_pkrtz(a, b));
}

// Packed tanh of 2 values. pe = f16x2{exp2(-|y0|), exp2(-|y1|)}, ps carries
// sign bits of (y0,y1).  r = 1/(1+e') via f16 Newton; tanh|y| = 2r-1; bfi sign.
__device__ __forceinline__ int tanh2(int pe, int ps) {
  h2v e = __builtin_bit_cast(h2v, pe);
  h2v d = e + (_Float16)1.0f;                      // d in (1,2]
  h2v r = d * (_Float16)(-8.0f / 17.0f) + (_Float16)(24.0f / 17.0f);
  r = r * ((_Float16)2.0f - d * r);                // NR1
  r = r * ((_Float16)2.0f - d * r);                // NR2 -> f16 rounding
  h2v g = r * (_Float16)2.0f - (_Float16)1.0f;     // tanh(|y|) in [0,1)
  int gi = __builtin_bit_cast(int, g);
  return (ps & 0x80008000) | (gi & 0x7fff7fff);    // copysign (v_bfi)
}

#if __has_builtin(__builtin_amdgcn_permlane32_swap) && __has_builtin(__builtin_amdgcn_permlane16_swap)
#define HAVE_SWAP 1
#else
#define HAVE_SWAP 0
#endif

// tanh both accumulator tiles (8 f32), pack, redistribute into next B-frag.
__device__ __forceinline__ H8 make_bfrag(f4v a0, f4v a1, int addrA, int addrB,
                                         bool tsel) {
  float e00 = fexp2(-__builtin_fabsf(a0[0])), e01 = fexp2(-__builtin_fabsf(a0[1]));
  float e02 = fexp2(-__builtin_fabsf(a0[2])), e03 = fexp2(-__builtin_fabsf(a0[3]));
  float e10 = fexp2(-__builtin_fabsf(a1[0])), e11 = fexp2(-__builtin_fabsf(a1[1]));
  float e12 = fexp2(-__builtin_fabsf(a1[2])), e13 = fexp2(-__builtin_fabsf(a1[3]));
  int A0 = tanh2(pkrtz(e00, e01), pkrtz(a0[0], a0[1]));  // tile0 units (4i,4i+1)
  int A1 = tanh2(pkrtz(e02, e03), pkrtz(a0[2], a0[3]));  // tile0 units (4i+2,4i+3)
  int B0 = tanh2(pkrtz(e10, e11), pkrtz(a1[0], a1[1]));  // tile1
  int B1 = tanh2(pkrtz(e12, e13), pkrtz(a1[2], a1[3]));
  H8 hf;
#if HAVE_SWAP
  // (pA,qA) = swap32(A0,B0): pA=[A0Q0,A0Q1,B0Q0,B0Q1], qA=[A0Q2,A0Q3,B0Q2,B0Q3]
  // (w0,w2) = swap16(pA,qA): w0=[A0Q0,A0Q2,B0Q0,B0Q2], w2=[A0Q1,A0Q3,B0Q1,B0Q3]
  u2v sA = __builtin_amdgcn_permlane32_swap((unsigned)A0, (unsigned)B0, false, false);
  u2v wA = __builtin_amdgcn_permlane16_swap(sA[0], sA[1], false, false);
  u2v sB = __builtin_amdgcn_permlane32_swap((unsigned)A1, (unsigned)B1, false, false);
  u2v wB = __builtin_amdgcn_permlane16_swap(sB[0], sB[1], false, false);
  hf.i[0] = (int)wA[0];
  hf.i[1] = (int)wB[0];
  hf.i[2] = (int)wA[1];
  hf.i[3] = (int)wB[1];
  (void)addrA; (void)addrB; (void)tsel;
#else
  int r0a = __builtin_amdgcn_ds_bpermute(addrA, A0);
  int r0b = __builtin_amdgcn_ds_bpermute(addrA, B0);
  int r1a = __builtin_amdgcn_ds_bpermute(addrA, A1);
  int r1b = __builtin_amdgcn_ds_bpermute(addrA, B1);
  int r2a = __builtin_amdgcn_ds_bpermute(addrB, A0);
  int r2b = __builtin_amdgcn_ds_bpermute(addrB, B0);
  int r3a = __builtin_amdgcn_ds_bpermute(addrB, A1);
  int r3b = __builtin_amdgcn_ds_bpermute(addrB, B1);
  hf.i[0] = tsel ? r0b : r0a;
  hf.i[1] = tsel ? r1b : r1a;
  hf.i[2] = tsel ? r2b : r2a;
  hf.i[3] = tsel ? r3b : r3a;
#endif
  return hf;
}

extern "C" __global__ void __launch_bounds__(BLOCK_THREADS, 4) pfnn_kernel(
    const float* __restrict__ X,
    const float* __restrict__ W0, const float* __restrict__ B0,
    const float* __restrict__ W1, const float* __restrict__ B1,
    const float* __restrict__ W2, const float* __restrict__ B2,
    const float* __restrict__ W3, const float* __restrict__ B3,
    float* __restrict__ Out) {
  __shared__ alignas(16) _Float16 lWT0[4][32][4];    // [b][u][k] k<3: s*W0, k==3: s*b0
  __shared__ alignas(16) _Float16 lWT1[4][32][40];   // [b][u][k], rows padded to 80B
  __shared__ alignas(16) _Float16 lWT2[4][32][40];
  __shared__ alignas(16) float lB1[4][32];           // s*b1 (MFMA C operand)
  __shared__ alignas(16) float lB2[4][32];
  __shared__ alignas(16) _Float16 lW3h[4][32];       // raw W3 (L3 has no tanh)
  __shared__ float lb3[4];

  const int tid = threadIdx.x;
  for (int idx = tid; idx < 512; idx += BLOCK_THREADS) {
    int b = idx >> 7, u = (idx >> 2) & 31, k = idx & 3;
    float v = (k < 3) ? W0[(b * 3 + k) * 32 + u] : B0[b * 32 + u];
    lWT0[b][u][k] = (_Float16)(v * TANH_SCALE);
  }
  for (int idx = tid; idx < 4096; idx += BLOCK_THREADS) {
    int b = idx >> 10, k = (idx >> 5) & 31, u = idx & 31;
    lWT1[b][u][k] = (_Float16)(W1[idx] * TANH_SCALE);
    lWT2[b][u][k] = (_Float16)(W2[idx] * TANH_SCALE);
  }
  for (int idx = tid; idx < 128; idx += BLOCK_THREADS) {
    int b = idx >> 5, u = idx & 31;
    lB1[b][u] = B1[idx] * TANH_SCALE;
    lB2[b][u] = B2[idx] * TANH_SCALE;
    lW3h[b][u] = (_Float16)W3[idx];
  }
  if (tid < 4) lb3[tid] = B3[tid];
  __syncthreads();

  const int lane = tid & 63;
  const int wv = tid >> 6;       // 0..7
  const int g = lane >> 4;       // k-group
  const int p = lane & 15;       // point within subtile
  const bool g0 = (g == 0);
  const bool tsel = (g >= 2);
  const int addrA = (((g & 1) << 5) | p) << 2;  // fallback-path addresses
  const int addrB = addrA + 64;
  const int addrP = p << 2;                      // gather: src lane p

  const int nblk = NPTS >> 6;    // 64 points per wave-iteration
  for (int blk = blockIdx.x * 8 + wv; blk < nblk; blk += GRID_BLOCKS * 8) {
    const int base = blk << 6;
    const float* xp = X + (size_t)(base + lane) * 3;
    float x0 = xp[0], x1 = xp[1], x2 = xp[2];

    // Branch-independent x B-fragments (k<3: x, k==3: 1.0), zero for g>0.
    H8 xf[4];
#pragma unroll
    for (int s = 0; s < 4; ++s) {
      int a = (16 * s + p) << 2;
      float fx0 = __int_as_float(__builtin_amdgcn_ds_bpermute(a, __float_as_int(x0)));
      float fx1 = __int_as_float(__builtin_amdgcn_ds_bpermute(a, __float_as_int(x1)));
      float fx2 = __int_as_float(__builtin_amdgcn_ds_bpermute(a, __float_as_int(x2)));
      int q0 = pkrtz(fx0, fx1);
      int q1 = pkrtz(fx2, 1.0f);
      xf[s].i[0] = g0 ? q0 : 0;
      xf[s].i[1] = g0 ? q1 : 0;
      xf[s].i[2] = 0;
      xf[s].i[3] = 0;
    }

    f4v res4;
#pragma unroll
    for (int b = 0; b < 4; ++b) {
      // Hoisted per-branch weight fragments.
      H8 w0a[2];
      h8v w1a[2], w2a[2];
      f4v bs1[2], bs2[2];
#pragma unroll
      for (int t = 0; t < 2; ++t) {
        const int* q = (const int*)&lWT0[b][16 * t + p][0];
        int q0 = q[0], q1 = q[1];
        w0a[t].i[0] = g0 ? q0 : 0;
        w0a[t].i[1] = g0 ? q1 : 0;
        w0a[t].i[2] = 0;
        w0a[t].i[3] = 0;
        w1a[t] = *(const h8v*)&lWT1[b][16 * t + p][8 * g];
        w2a[t] = *(const h8v*)&lWT2[b][16 * t + p][8 * g];
        bs1[t] = *(const f4v*)&lB1[b][16 * t + 4 * g];
        bs2[t] = *(const f4v*)&lB2[b][16 * t + 4 * g];
      }
      // L3 A-fragment: W3^T in row 0 (lanes with p==0 hold w3[8g..8g+7]).
      h8v w3z = {0, 0, 0, 0, 0, 0, 0, 0};
      h8v w3a = (p == 0) ? *(const h8v*)&lW3h[b][8 * g] : w3z;
      float b3s = lb3[b];
      float res = 0.0f;

#pragma unroll
      for (int s = 0; s < 4; ++s) {
        f4v z = {0.f, 0.f, 0.f, 0.f};
        // L0 (bias folded in k==3 row of W0')
        f4v a0 = __builtin_amdgcn_mfma_f32_16x16x32_f16(w0a[0].h, xf[s].h, z, 0, 0, 0);
        f4v a1 = __builtin_amdgcn_mfma_f32_16x16x32_f16(w0a[1].h, xf[s].h, z, 0, 0, 0);
        H8 hf = make_bfrag(a0, a1, addrA, addrB, tsel);
        // L1
        a0 = __builtin_amdgcn_mfma_f32_16x16x32_f16(w1a[0], hf.h, bs1[0], 0, 0, 0);
        a1 = __builtin_amdgcn_mfma_f32_16x16x32_f16(w1a[1], hf.h, bs1[1], 0, 0, 0);
        hf = make_bfrag(a0, a1, addrA, addrB, tsel);
        // L2
        a0 = __builtin_amdgcn_mfma_f32_16x16x32_f16(w2a[0], hf.h, bs2[0], 0, 0, 0);
        a1 = __builtin_amdgcn_mfma_f32_16x16x32_f16(w2a[1], hf.h, bs2[1], 0, 0, 0);
        hf = make_bfrag(a0, a1, addrA, addrB, tsel);
        // L3: one MFMA; row 0 (reg 0, lanes 0..15) = out[point p]
        f4v o = __builtin_amdgcn_mfma_f32_16x16x32_f16(w3a, hf.h, z, 0, 0, 0);
        // Lane l=16g+p needs subtile g's value for point p (lives in lane p).
        float rr = __int_as_float(__builtin_amdgcn_ds_bpermute(addrP, __float_as_int(o[0])));
        res = (g == s) ? rr : res;
      }
      res4[b] = res + b3s;
    }
    *(f4v*)(Out + (size_t)(base + lane) * 4) = res4;   // one 16B store/point
  }
}

extern "C" void kernel_launch(void* const* d_in, const int* in_sizes, int n_in,
                              void* d_out, int out_size, void* d_ws, size_t ws_size,
                              hipStream_t stream) {
  (void)in_sizes; (void)n_in; (void)out_size; (void)d_ws; (void)ws_size;
  const float* X  = (const float*)d_in[0];
  const float* W0 = (const float*)d_in[1];
  const float* B0 = (const float*)d_in[2];
  const float* W1 = (const float*)d_in[3];
  const float* B1 = (const float*)d_in[4];
  const float* W2 = (const float*)d_in[5];
  const float* B2 = (const float*)d_in[6];
  const float* W3 = (const float*)d_in[7];
  const float* B3 = (const float*)d_in[8];
  float* Out = (float*)d_out;
  pfnn_kernel<<<dim3(GRID_BLOCKS), dim3(BLOCK_THREADS), 0, stream>>>(
      X, W0, B0, W1, B1, W2, B2, W3, B3, Out);
}

// Round 5
// 198.504 us; speedup vs baseline: 2.2898x; 1.1671x over previous
//
#include <hip/hip_runtime.h>
#include <hip/hip_bf16.h>

// PFNN: out[n][b] = L3(tanh(L2(tanh(L1(tanh(L0(x)))))))  B=4, H=32, D_IN=3,
// N=1048576.  f16 MFMA 16x16x32 computing out^T = W^T h^T per 16-pt subtile.
// R4 change vs R3: __launch_bounds__(512) ONLY (no min-waves).  R3's (512,4)
// gave the allocator a 128-reg budget which it split arch-VGPR=64 + AGPR,
// spilling the ~100-reg live set -> 521 MB scratch traffic, 3 TB/s,
// scratch-BW-bound at 173us with VALUBusy 53%.  Occupancy is NOT the
// binding resource (R1: 79% VALUBusy at ~2.4 waves/SIMD), issue rate is.
// Keep: permlane32/16_swap bfrag redistribution (bank conflicts 1e7->1.3e6),
// 1-trans tanh (exp2 neg-abs + packed-f16 Newton), single float4 store.
// Weights/biases of L0..L2 pre-scaled by 2*log2(e) so y is in exp2 domain.

#define NPTS 1048576
constexpr int GRID_BLOCKS = 1024;
constexpr int BLOCK_THREADS = 512;           // 8 waves
constexpr float TANH_SCALE = 2.885390081777927f;  // 2*log2(e)

typedef _Float16 h8v __attribute__((ext_vector_type(8)));
typedef _Float16 h2v __attribute__((ext_vector_type(2)));
typedef float f4v __attribute__((ext_vector_type(4)));
typedef unsigned int u2v __attribute__((ext_vector_type(2)));

union H8 { h8v h; int i[4]; };

__device__ __forceinline__ float fexp2(float x) {
#if __has_builtin(__builtin_amdgcn_exp2f)
  return __builtin_amdgcn_exp2f(x);
#else
  float r;
  asm("v_exp_f32 %0, %1" : "=v"(r) : "v"(x));
  return r;
#endif
}

__device__ __forceinline__ int pkrtz(float a, float b) {
  return __builtin_bit_cast(int, __builtin_amdgcn_cvt_pkrtz(a, b));
}

// Packed tanh of 2 values. pe = f16x2{exp2(-|y0|), exp2(-|y1|)}, ps carries
// sign bits of (y0,y1).  r = 1/(1+e') via f16 Newton; tanh|y| = 2r-1; bfi sign.
__device__ __forceinline__ int tanh2(int pe, int ps) {
  h2v e = __builtin_bit_cast(h2v, pe);
  h2v d = e + (_Float16)1.0f;                      // d in (1,2]
  h2v r = d * (_Float16)(-8.0f / 17.0f) + (_Float16)(24.0f / 17.0f);
  r = r * ((_Float16)2.0f - d * r);                // NR1
  r = r * ((_Float16)2.0f - d * r);                // NR2 -> f16 rounding
  h2v g = r * (_Float16)2.0f - (_Float16)1.0f;     // tanh(|y|) in [0,1)
  int gi = __builtin_bit_cast(int, g);
  return (ps & 0x80008000) | (gi & 0x7fff7fff);    // copysign (v_bfi)
}

// tanh both accumulator tiles (8 f32), pack, redistribute into next B-frag.
// Quadrant Qi of the wave holds tile0 pairs (A0,A1), tile1 pairs (B0,B1);
// target frag word layout: w0=[A0Q0,A0Q2,B0Q0,B0Q2] etc =
// swap16(swap32(A0,B0)) / swap16(swap32(A1,B1)).
__device__ __forceinline__ H8 make_bfrag(f4v a0, f4v a1) {
  float e00 = fexp2(-__builtin_fabsf(a0[0])), e01 = fexp2(-__builtin_fabsf(a0[1]));
  float e02 = fexp2(-__builtin_fabsf(a0[2])), e03 = fexp2(-__builtin_fabsf(a0[3]));
  float e10 = fexp2(-__builtin_fabsf(a1[0])), e11 = fexp2(-__builtin_fabsf(a1[1]));
  float e12 = fexp2(-__builtin_fabsf(a1[2])), e13 = fexp2(-__builtin_fabsf(a1[3]));
  int A0 = tanh2(pkrtz(e00, e01), pkrtz(a0[0], a0[1]));  // tile0 units (4i,4i+1)
  int A1 = tanh2(pkrtz(e02, e03), pkrtz(a0[2], a0[3]));  // tile0 units (4i+2,4i+3)
  int B0 = tanh2(pkrtz(e10, e11), pkrtz(a1[0], a1[1]));  // tile1
  int B1 = tanh2(pkrtz(e12, e13), pkrtz(a1[2], a1[3]));
  u2v sA = __builtin_amdgcn_permlane32_swap((unsigned)A0, (unsigned)B0, false, false);
  u2v wA = __builtin_amdgcn_permlane16_swap(sA[0], sA[1], false, false);
  u2v sB = __builtin_amdgcn_permlane32_swap((unsigned)A1, (unsigned)B1, false, false);
  u2v wB = __builtin_amdgcn_permlane16_swap(sB[0], sB[1], false, false);
  H8 hf;
  hf.i[0] = (int)wA[0];
  hf.i[1] = (int)wB[0];
  hf.i[2] = (int)wA[1];
  hf.i[3] = (int)wB[1];
  return hf;
}

extern "C" __global__ void __launch_bounds__(BLOCK_THREADS) pfnn_kernel(
    const float* __restrict__ X,
    const float* __restrict__ W0, const float* __restrict__ B0,
    const float* __restrict__ W1, const float* __restrict__ B1,
    const float* __restrict__ W2, const float* __restrict__ B2,
    const float* __restrict__ W3, const float* __restrict__ B3,
    float* __restrict__ Out) {
  __shared__ alignas(16) _Float16 lWT0[4][32][4];    // [b][u][k] k<3: s*W0, k==3: s*b0
  __shared__ alignas(16) _Float16 lWT1[4][32][40];   // [b][u][k], rows padded to 80B
  __shared__ alignas(16) _Float16 lWT2[4][32][40];
  __shared__ alignas(16) float lB1[4][32];           // s*b1 (MFMA C operand)
  __shared__ alignas(16) float lB2[4][32];
  __shared__ alignas(16) _Float16 lW3h[4][32];       // raw W3 (L3 has no tanh)
  __shared__ float lb3[4];

  const int tid = threadIdx.x;
  for (int idx = tid; idx < 512; idx += BLOCK_THREADS) {
    int b = idx >> 7, u = (idx >> 2) & 31, k = idx & 3;
    float v = (k < 3) ? W0[(b * 3 + k) * 32 + u] : B0[b * 32 + u];
    lWT0[b][u][k] = (_Float16)(v * TANH_SCALE);
  }
  for (int idx = tid; idx < 4096; idx += BLOCK_THREADS) {
    int b = idx >> 10, k = (idx >> 5) & 31, u = idx & 31;
    lWT1[b][u][k] = (_Float16)(W1[idx] * TANH_SCALE);
    lWT2[b][u][k] = (_Float16)(W2[idx] * TANH_SCALE);
  }
  for (int idx = tid; idx < 128; idx += BLOCK_THREADS) {
    int b = idx >> 5, u = idx & 31;
    lB1[b][u] = B1[idx] * TANH_SCALE;
    lB2[b][u] = B2[idx] * TANH_SCALE;
    lW3h[b][u] = (_Float16)W3[idx];
  }
  if (tid < 4) lb3[tid] = B3[tid];
  __syncthreads();

  const int lane = tid & 63;
  const int wv = tid >> 6;       // 0..7
  const int g = lane >> 4;       // k-group
  const int p = lane & 15;       // point within subtile
  const bool g0 = (g == 0);
  const int addrP = p << 2;      // gather: src lane p

  const int nblk = NPTS >> 6;    // 64 points per wave-iteration
  for (int blk = blockIdx.x * 8 + wv; blk < nblk; blk += GRID_BLOCKS * 8) {
    const int base = blk << 6;
    const float* xp = X + (size_t)(base + lane) * 3;
    float x0 = xp[0], x1 = xp[1], x2 = xp[2];

    // Branch-independent x B-fragments (k<3: x, k==3: 1.0), zero for g>0.
    H8 xf[4];
#pragma unroll
    for (int s = 0; s < 4; ++s) {
      int a = (16 * s + p) << 2;
      float fx0 = __int_as_float(__builtin_amdgcn_ds_bpermute(a, __float_as_int(x0)));
      float fx1 = __int_as_float(__builtin_amdgcn_ds_bpermute(a, __float_as_int(x1)));
      float fx2 = __int_as_float(__builtin_amdgcn_ds_bpermute(a, __float_as_int(x2)));
      int q0 = pkrtz(fx0, fx1);
      int q1 = pkrtz(fx2, 1.0f);
      xf[s].i[0] = g0 ? q0 : 0;
      xf[s].i[1] = g0 ? q1 : 0;
      xf[s].i[2] = 0;
      xf[s].i[3] = 0;
    }

    f4v res4;
#pragma unroll
    for (int b = 0; b < 4; ++b) {
      // Hoisted per-branch weight fragments.
      H8 w0a[2];
      h8v w1a[2], w2a[2];
      f4v bs1[2], bs2[2];
#pragma unroll
      for (int t = 0; t < 2; ++t) {
        const int* q = (const int*)&lWT0[b][16 * t + p][0];
        int q0 = q[0], q1 = q[1];
        w0a[t].i[0] = g0 ? q0 : 0;
        w0a[t].i[1] = g0 ? q1 : 0;
        w0a[t].i[2] = 0;
        w0a[t].i[3] = 0;
        w1a[t] = *(const h8v*)&lWT1[b][16 * t + p][8 * g];
        w2a[t] = *(const h8v*)&lWT2[b][16 * t + p][8 * g];
        bs1[t] = *(const f4v*)&lB1[b][16 * t + 4 * g];
        bs2[t] = *(const f4v*)&lB2[b][16 * t + 4 * g];
      }
      // L3 A-fragment: W3^T in row 0 (lanes with p==0 hold w3[8g..8g+7]).
      h8v w3z = {0, 0, 0, 0, 0, 0, 0, 0};
      h8v w3a = (p == 0) ? *(const h8v*)&lW3h[b][8 * g] : w3z;
      float b3s = lb3[b];
      float res = 0.0f;

#pragma unroll
      for (int s = 0; s < 4; ++s) {
        f4v z = {0.f, 0.f, 0.f, 0.f};
        // L0 (bias folded in k==3 row of W0')
        f4v a0 = __builtin_amdgcn_mfma_f32_16x16x32_f16(w0a[0].h, xf[s].h, z, 0, 0, 0);
        f4v a1 = __builtin_amdgcn_mfma_f32_16x16x32_f16(w0a[1].h, xf[s].h, z, 0, 0, 0);
        H8 hf = make_bfrag(a0, a1);
        // L1
        a0 = __builtin_amdgcn_mfma_f32_16x16x32_f16(w1a[0], hf.h, bs1[0], 0, 0, 0);
        a1 = __builtin_amdgcn_mfma_f32_16x16x32_f16(w1a[1], hf.h, bs1[1], 0, 0, 0);
        hf = make_bfrag(a0, a1);
        // L2
        a0 = __builtin_amdgcn_mfma_f32_16x16x32_f16(w2a[0], hf.h, bs2[0], 0, 0, 0);
        a1 = __builtin_amdgcn_mfma_f32_16x16x32_f16(w2a[1], hf.h, bs2[1], 0, 0, 0);
        hf = make_bfrag(a0, a1);
        // L3: one MFMA; row 0 (reg 0, lanes 0..15) = out[point p]
        f4v o = __builtin_amdgcn_mfma_f32_16x16x32_f16(w3a, hf.h, z, 0, 0, 0);
        // Lane l=16g+p needs subtile g's value for point p (lives in lane p).
        float rr = __int_as_float(__builtin_amdgcn_ds_bpermute(addrP, __float_as_int(o[0])));
        res = (g == s) ? rr : res;
      }
      res4[b] = res + b3s;
    }
    *(f4v*)(Out + (size_t)(base + lane) * 4) = res4;   // one 16B store/point
  }
}

extern "C" void kernel_launch(void* const* d_in, const int* in_sizes, int n_in,
                              void* d_out, int out_size, void* d_ws, size_t ws_size,
                              hipStream_t stream) {
  (void)in_sizes; (void)n_in; (void)out_size; (void)d_ws; (void)ws_size;
  const float* X  = (const float*)d_in[0];
  const float* W0 = (const float*)d_in[1];
  const float* B0 = (const float*)d_in[2];
  const float* W1 = (const float*)d_in[3];
  const float* B1 = (const float*)d_in[4];
  const float* W2 = (const float*)d_in[5];
  const float* B2 = (const float*)d_in[6];
  const float* W3 = (const float*)d_in[7];
  const float* B3 = (const float*)d_in[8];
  float* Out = (float*)d_out;
  pfnn_kernel<<<dim3(GRID_BLOCKS), dim3(BLOCK_THREADS), 0, stream>>>(
      X, W0, B0, W1, B1, W2, B2, W3, B3, Out);
}

// Round 6
// 195.011 us; speedup vs baseline: 2.3308x; 1.0179x over previous
//
#include <hip/hip_runtime.h>
#include <hip/hip_bf16.h>

// PFNN: out[n][b] = L3(tanh(L2(tanh(L1(tanh(L0(x)))))))  B=4, H=32, D_IN=3,
// N=1048576.  f16 MFMA 16x16x32 computing out^T = W^T h^T per 16-pt subtile.
// R5 changes vs R4 (137us, VALUBusy 66%, Occupancy 19% -> LATENCY-bound:
// 112 arch VGPR + AGPR ~ 168 effective -> 3 waves/SIMD, and the 8-wave block
// granularity (2 waves/SIMD/block) rounded residency down to 1 block/CU):
//  - block = 256 (4 waves = 1 wave/SIMD granularity): residency becomes
//    floor(512/regs) waves/SIMD exactly, no quantization loss.
//  - grid = 4096: each wave does exactly ONE 64-point block; no grid-stride
//    loop state; HW scheduler backfills.
//  - s-loop unroll 2 (was 4): halves in-flight chain registers to push
//    combined regs toward <=128 -> 4 waves/SIMD.
// Keep: permlane32/16_swap bfrag redistribution, 1-trans tanh (exp2 neg-abs
// + packed-f16 Newton), bias in MFMA C / W0 k=3 row, single float4 store.
// Weights/biases of L0..L2 pre-scaled by 2*log2(e) so y is in exp2 domain.

#define NPTS 1048576
constexpr int BLOCK_THREADS = 256;           // 4 waves = 1 wave/SIMD
constexpr int GRID_BLOCKS = NPTS / 64 / 4;   // 4096: one 64-pt tile per wave
constexpr float TANH_SCALE = 2.885390081777927f;  // 2*log2(e)

typedef _Float16 h8v __attribute__((ext_vector_type(8)));
typedef _Float16 h2v __attribute__((ext_vector_type(2)));
typedef float f4v __attribute__((ext_vector_type(4)));
typedef unsigned int u2v __attribute__((ext_vector_type(2)));

union H8 { h8v h; int i[4]; };

__device__ __forceinline__ float fexp2(float x) {
#if __has_builtin(__builtin_amdgcn_exp2f)
  return __builtin_amdgcn_exp2f(x);
#else
  float r;
  asm("v_exp_f32 %0, %1" : "=v"(r) : "v"(x));
  return r;
#endif
}

__device__ __forceinline__ int pkrtz(float a, float b) {
  return __builtin_bit_cast(int, __builtin_amdgcn_cvt_pkrtz(a, b));
}

// Packed tanh of 2 values. pe = f16x2{exp2(-|y0|), exp2(-|y1|)}, ps carries
// sign bits of (y0,y1).  r = 1/(1+e') via f16 Newton; tanh|y| = 2r-1; bfi sign.
__device__ __forceinline__ int tanh2(int pe, int ps) {
  h2v e = __builtin_bit_cast(h2v, pe);
  h2v d = e + (_Float16)1.0f;                      // d in (1,2]
  h2v r = d * (_Float16)(-8.0f / 17.0f) + (_Float16)(24.0f / 17.0f);
  r = r * ((_Float16)2.0f - d * r);                // NR1
  r = r * ((_Float16)2.0f - d * r);                // NR2 -> f16 rounding
  h2v g = r * (_Float16)2.0f - (_Float16)1.0f;     // tanh(|y|) in [0,1)
  int gi = __builtin_bit_cast(int, g);
  return (ps & 0x80008000) | (gi & 0x7fff7fff);    // copysign (v_bfi)
}

// tanh both accumulator tiles (8 f32), pack, redistribute into next B-frag.
// Quadrant Qi of the wave holds tile0 pairs (A0,A1), tile1 pairs (B0,B1);
// target frag word layout: w0=[A0Q0,A0Q2,B0Q0,B0Q2] etc =
// swap16(swap32(A0,B0)) / swap16(swap32(A1,B1)).
__device__ __forceinline__ H8 make_bfrag(f4v a0, f4v a1) {
  float e00 = fexp2(-__builtin_fabsf(a0[0])), e01 = fexp2(-__builtin_fabsf(a0[1]));
  float e02 = fexp2(-__builtin_fabsf(a0[2])), e03 = fexp2(-__builtin_fabsf(a0[3]));
  float e10 = fexp2(-__builtin_fabsf(a1[0])), e11 = fexp2(-__builtin_fabsf(a1[1]));
  float e12 = fexp2(-__builtin_fabsf(a1[2])), e13 = fexp2(-__builtin_fabsf(a1[3]));
  int A0 = tanh2(pkrtz(e00, e01), pkrtz(a0[0], a0[1]));  // tile0 units (4i,4i+1)
  int A1 = tanh2(pkrtz(e02, e03), pkrtz(a0[2], a0[3]));  // tile0 units (4i+2,4i+3)
  int B0 = tanh2(pkrtz(e10, e11), pkrtz(a1[0], a1[1]));  // tile1
  int B1 = tanh2(pkrtz(e12, e13), pkrtz(a1[2], a1[3]));
  u2v sA = __builtin_amdgcn_permlane32_swap((unsigned)A0, (unsigned)B0, false, false);
  u2v wA = __builtin_amdgcn_permlane16_swap(sA[0], sA[1], false, false);
  u2v sB = __builtin_amdgcn_permlane32_swap((unsigned)A1, (unsigned)B1, false, false);
  u2v wB = __builtin_amdgcn_permlane16_swap(sB[0], sB[1], false, false);
  H8 hf;
  hf.i[0] = (int)wA[0];
  hf.i[1] = (int)wB[0];
  hf.i[2] = (int)wA[1];
  hf.i[3] = (int)wB[1];
  return hf;
}

extern "C" __global__ void __launch_bounds__(BLOCK_THREADS) pfnn_kernel(
    const float* __restrict__ X,
    const float* __restrict__ W0, const float* __restrict__ B0,
    const float* __restrict__ W1, const float* __restrict__ B1,
    const float* __restrict__ W2, const float* __restrict__ B2,
    const float* __restrict__ W3, const float* __restrict__ B3,
    float* __restrict__ Out) {
  __shared__ alignas(16) _Float16 lWT0[4][32][4];    // [b][u][k] k<3: s*W0, k==3: s*b0
  __shared__ alignas(16) _Float16 lWT1[4][32][40];   // [b][u][k], rows padded to 80B
  __shared__ alignas(16) _Float16 lWT2[4][32][40];
  __shared__ alignas(16) float lB1[4][32];           // s*b1 (MFMA C operand)
  __shared__ alignas(16) float lB2[4][32];
  __shared__ alignas(16) _Float16 lW3h[4][32];       // raw W3 (L3 has no tanh)
  __shared__ float lb3[4];

  const int tid = threadIdx.x;
  for (int idx = tid; idx < 512; idx += BLOCK_THREADS) {
    int b = idx >> 7, u = (idx >> 2) & 31, k = idx & 3;
    float v = (k < 3) ? W0[(b * 3 + k) * 32 + u] : B0[b * 32 + u];
    lWT0[b][u][k] = (_Float16)(v * TANH_SCALE);
  }
  for (int idx = tid; idx < 4096; idx += BLOCK_THREADS) {
    int b = idx >> 10, k = (idx >> 5) & 31, u = idx & 31;
    lWT1[b][u][k] = (_Float16)(W1[idx] * TANH_SCALE);
    lWT2[b][u][k] = (_Float16)(W2[idx] * TANH_SCALE);
  }
  for (int idx = tid; idx < 128; idx += BLOCK_THREADS) {
    int b = idx >> 5, u = idx & 31;
    lB1[b][u] = B1[idx] * TANH_SCALE;
    lB2[b][u] = B2[idx] * TANH_SCALE;
    lW3h[b][u] = (_Float16)W3[idx];
  }
  if (tid < 4) lb3[tid] = B3[tid];
  __syncthreads();

  const int lane = tid & 63;
  const int wv = tid >> 6;       // 0..3
  const int g = lane >> 4;       // k-group
  const int p = lane & 15;       // point within subtile
  const bool g0 = (g == 0);
  const int addrP = p << 2;      // gather: src lane p

  const int blk = blockIdx.x * 4 + wv;   // one 64-point tile per wave
  const int base = blk << 6;
  const float* xp = X + (size_t)(base + lane) * 3;
  float x0 = xp[0], x1 = xp[1], x2 = xp[2];

  // Branch-independent x B-fragments (k<3: x, k==3: 1.0), zero for g>0.
  H8 xf[4];
#pragma unroll
  for (int s = 0; s < 4; ++s) {
    int a = (16 * s + p) << 2;
    float fx0 = __int_as_float(__builtin_amdgcn_ds_bpermute(a, __float_as_int(x0)));
    float fx1 = __int_as_float(__builtin_amdgcn_ds_bpermute(a, __float_as_int(x1)));
    float fx2 = __int_as_float(__builtin_amdgcn_ds_bpermute(a, __float_as_int(x2)));
    int q0 = pkrtz(fx0, fx1);
    int q1 = pkrtz(fx2, 1.0f);
    xf[s].i[0] = g0 ? q0 : 0;
    xf[s].i[1] = g0 ? q1 : 0;
    xf[s].i[2] = 0;
    xf[s].i[3] = 0;
  }

  f4v res4;
#pragma unroll
  for (int b = 0; b < 4; ++b) {
    // Hoisted per-branch weight fragments.
    H8 w0a[2];
    h8v w1a[2], w2a[2];
    f4v bs1[2], bs2[2];
#pragma unroll
    for (int t = 0; t < 2; ++t) {
      const int* q = (const int*)&lWT0[b][16 * t + p][0];
      int q0 = q[0], q1 = q[1];
      w0a[t].i[0] = g0 ? q0 : 0;
      w0a[t].i[1] = g0 ? q1 : 0;
      w0a[t].i[2] = 0;
      w0a[t].i[3] = 0;
      w1a[t] = *(const h8v*)&lWT1[b][16 * t + p][8 * g];
      w2a[t] = *(const h8v*)&lWT2[b][16 * t + p][8 * g];
      bs1[t] = *(const f4v*)&lB1[b][16 * t + 4 * g];
      bs2[t] = *(const f4v*)&lB2[b][16 * t + 4 * g];
    }
    // L3 A-fragment: W3^T in row 0 (lanes with p==0 hold w3[8g..8g+7]).
    h8v w3z = {0, 0, 0, 0, 0, 0, 0, 0};
    h8v w3a = (p == 0) ? *(const h8v*)&lW3h[b][8 * g] : w3z;
    float b3s = lb3[b];
    float res = 0.0f;

#pragma unroll 2     // half the in-flight chain registers vs full unroll
    for (int s = 0; s < 4; ++s) {
      f4v z = {0.f, 0.f, 0.f, 0.f};
      // L0 (bias folded in k==3 row of W0')
      f4v a0 = __builtin_amdgcn_mfma_f32_16x16x32_f16(w0a[0].h, xf[s].h, z, 0, 0, 0);
      f4v a1 = __builtin_amdgcn_mfma_f32_16x16x32_f16(w0a[1].h, xf[s].h, z, 0, 0, 0);
      H8 hf = make_bfrag(a0, a1);
      // L1
      a0 = __builtin_amdgcn_mfma_f32_16x16x32_f16(w1a[0], hf.h, bs1[0], 0, 0, 0);
      a1 = __builtin_amdgcn_mfma_f32_16x16x32_f16(w1a[1], hf.h, bs1[1], 0, 0, 0);
      hf = make_bfrag(a0, a1);
      // L2
      a0 = __builtin_amdgcn_mfma_f32_16x16x32_f16(w2a[0], hf.h, bs2[0], 0, 0, 0);
      a1 = __builtin_amdgcn_mfma_f32_16x16x32_f16(w2a[1], hf.h, bs2[1], 0, 0, 0);
      hf = make_bfrag(a0, a1);
      // L3: one MFMA; row 0 (reg 0, lanes 0..15) = out[point p]
      f4v o = __builtin_amdgcn_mfma_f32_16x16x32_f16(w3a, hf.h, z, 0, 0, 0);
      // Lane l=16g+p needs subtile g's value for point p (lives in lane p).
      float rr = __int_as_float(__builtin_amdgcn_ds_bpermute(addrP, __float_as_int(o[0])));
      res = (g == s) ? rr : res;
    }
    res4[b] = res + b3s;
  }
  *(f4v*)(Out + (size_t)(base + lane) * 4) = res4;   // one 16B store/point
}

extern "C" void kernel_launch(void* const* d_in, const int* in_sizes, int n_in,
                              void* d_out, int out_size, void* d_ws, size_t ws_size,
                              hipStream_t stream) {
  (void)in_sizes; (void)n_in; (void)out_size; (void)d_ws; (void)ws_size;
  const float* X  = (const float*)d_in[0];
  const float* W0 = (const float*)d_in[1];
  const float* B0 = (const float*)d_in[2];
  const float* W1 = (const float*)d_in[3];
  const float* B1 = (const float*)d_in[4];
  const float* W2 = (const float*)d_in[5];
  const float* B2 = (const float*)d_in[6];
  const float* W3 = (const float*)d_in[7];
  const float* B3 = (const float*)d_in[8];
  float* Out = (float*)d_out;
  pfnn_kernel<<<dim3(GRID_BLOCKS), dim3(BLOCK_THREADS), 0, stream>>>(
      X, W0, B0, W1, B1, W2, B2, W3, B3, Out);
}

// Round 7
// 169.270 us; speedup vs baseline: 2.6853x; 1.1521x over previous
//
#include <hip/hip_runtime.h>
#include <hip/hip_bf16.h>

// PFNN: out[n][b] = L3(tanh(L2(tanh(L1(tanh(L0(x)))))))  B=4, H=32, D_IN=3,
// N=1048576.  f16 MFMA 16x16x32 computing out^T = W^T h^T per 16-pt subtile.
// R6 vs R5 (139us, 4 waves/SIMD but compiler chose 44 arch VGPR -> 64MB
// scratch spill ate the occupancy gain):
//  - __launch_bounds__(256, 4): explicit 128-reg/wave budget; live set cut
//    to ~90 (xf kept as 2-word pairs, shared zeros) so it fits WITHOUT spill.
//  - tanh via degree-4 minimax poly in e=exp2(-|y|) (Chebyshev of
//    (1-e)/(1+e) on [0,1], max err ~4.4e-4): 4 v_pk_fma_f16 per pair vs
//    8-op Newton.  1 trans + ~6 full-rate per 2 values.
// Keep: permlane32/16_swap bfrag redistribution, bias in MFMA C / W0 k=3
// row, one 64-pt tile per wave (grid 4096x256), single float4 store.
// Weights/biases of L0..L2 pre-scaled by 2*log2(e) so y is in exp2 domain.

#define NPTS 1048576
constexpr int BLOCK_THREADS = 256;           // 4 waves = 1 wave/SIMD
constexpr int GRID_BLOCKS = NPTS / 64 / 4;   // 4096: one 64-pt tile per wave
constexpr float TANH_SCALE = 2.885390081777927f;  // 2*log2(e)

typedef _Float16 h8v __attribute__((ext_vector_type(8)));
typedef _Float16 h2v __attribute__((ext_vector_type(2)));
typedef float f4v __attribute__((ext_vector_type(4)));
typedef unsigned int u2v __attribute__((ext_vector_type(2)));

union H8 { h8v h; int i[4]; };

__device__ __forceinline__ float fexp2(float x) {
#if __has_builtin(__builtin_amdgcn_exp2f)
  return __builtin_amdgcn_exp2f(x);
#else
  float r;
  asm("v_exp_f32 %0, %1" : "=v"(r) : "v"(x));
  return r;
#endif
}

__device__ __forceinline__ int pkrtz(float a, float b) {
  return __builtin_bit_cast(int, __builtin_amdgcn_cvt_pkrtz(a, b));
}

// Packed tanh of 2 values from pe = f16x2{exp2(-|y0|),exp2(-|y1|)} and sign
// pair ps.  t(e) = minimax deg-4 poly of (1-e)/(1+e) on (0,1]; bfi sign.
__device__ __forceinline__ int tanh2p(int pe, int ps) {
  h2v e = __builtin_bit_cast(h2v, pe);
  h2v t = e * (_Float16)0.3137280f + (_Float16)-1.0845760f;
  t = e * t + (_Float16)1.7439296f;
  t = e * t + (_Float16)-1.9722144f;
  t = e * t + (_Float16)0.9994922f;
  int gi = __builtin_bit_cast(int, t);
  return (ps & 0x80008000) | (gi & 0x7fff7fff);    // copysign (v_bfi)
}

// tanh both accumulator tiles (8 f32), pack, redistribute into next B-frag.
// Quadrant Qi of the wave holds tile0 pairs (A0,A1), tile1 pairs (B0,B1);
// w0=[A0Q0,A0Q2,B0Q0,B0Q2] etc = swap16(swap32(A0,B0)) / swap16(swap32(A1,B1)).
__device__ __forceinline__ H8 make_bfrag(f4v a0, f4v a1) {
  float e00 = fexp2(-__builtin_fabsf(a0[0])), e01 = fexp2(-__builtin_fabsf(a0[1]));
  float e02 = fexp2(-__builtin_fabsf(a0[2])), e03 = fexp2(-__builtin_fabsf(a0[3]));
  float e10 = fexp2(-__builtin_fabsf(a1[0])), e11 = fexp2(-__builtin_fabsf(a1[1]));
  float e12 = fexp2(-__builtin_fabsf(a1[2])), e13 = fexp2(-__builtin_fabsf(a1[3]));
  int A0 = tanh2p(pkrtz(e00, e01), pkrtz(a0[0], a0[1]));  // tile0 units (4i,4i+1)
  int A1 = tanh2p(pkrtz(e02, e03), pkrtz(a0[2], a0[3]));  // tile0 units (4i+2,4i+3)
  int B0 = tanh2p(pkrtz(e10, e11), pkrtz(a1[0], a1[1]));  // tile1
  int B1 = tanh2p(pkrtz(e12, e13), pkrtz(a1[2], a1[3]));
  u2v sA = __builtin_amdgcn_permlane32_swap((unsigned)A0, (unsigned)B0, false, false);
  u2v wA = __builtin_amdgcn_permlane16_swap(sA[0], sA[1], false, false);
  u2v sB = __builtin_amdgcn_permlane32_swap((unsigned)A1, (unsigned)B1, false, false);
  u2v wB = __builtin_amdgcn_permlane16_swap(sB[0], sB[1], false, false);
  H8 hf;
  hf.i[0] = (int)wA[0];
  hf.i[1] = (int)wB[0];
  hf.i[2] = (int)wA[1];
  hf.i[3] = (int)wB[1];
  return hf;
}

extern "C" __global__ void __launch_bounds__(BLOCK_THREADS, 4) pfnn_kernel(
    const float* __restrict__ X,
    const float* __restrict__ W0, const float* __restrict__ B0,
    const float* __restrict__ W1, const float* __restrict__ B1,
    const float* __restrict__ W2, const float* __restrict__ B2,
    const float* __restrict__ W3, const float* __restrict__ B3,
    float* __restrict__ Out) {
  __shared__ alignas(16) _Float16 lWT0[4][32][4];    // [b][u][k] k<3: s*W0, k==3: s*b0
  __shared__ alignas(16) _Float16 lWT1[4][32][40];   // [b][u][k], rows padded to 80B
  __shared__ alignas(16) _Float16 lWT2[4][32][40];
  __shared__ alignas(16) float lB1[4][32];           // s*b1 (MFMA C operand)
  __shared__ alignas(16) float lB2[4][32];
  __shared__ alignas(16) _Float16 lW3h[4][32];       // raw W3 (L3 has no tanh)
  __shared__ float lb3[4];

  const int tid = threadIdx.x;
  for (int idx = tid; idx < 512; idx += BLOCK_THREADS) {
    int b = idx >> 7, u = (idx >> 2) & 31, k = idx & 3;
    float v = (k < 3) ? W0[(b * 3 + k) * 32 + u] : B0[b * 32 + u];
    lWT0[b][u][k] = (_Float16)(v * TANH_SCALE);
  }
  for (int idx = tid; idx < 4096; idx += BLOCK_THREADS) {
    int b = idx >> 10, k = (idx >> 5) & 31, u = idx & 31;
    lWT1[b][u][k] = (_Float16)(W1[idx] * TANH_SCALE);
    lWT2[b][u][k] = (_Float16)(W2[idx] * TANH_SCALE);
  }
  for (int idx = tid; idx < 128; idx += BLOCK_THREADS) {
    int b = idx >> 5, u = idx & 31;
    lB1[b][u] = B1[idx] * TANH_SCALE;
    lB2[b][u] = B2[idx] * TANH_SCALE;
    lW3h[b][u] = (_Float16)W3[idx];
  }
  if (tid < 4) lb3[tid] = B3[tid];
  __syncthreads();

  const int lane = tid & 63;
  const int wv = tid >> 6;       // 0..3
  const int g = lane >> 4;       // k-group
  const int p = lane & 15;       // point within subtile
  const bool g0 = (g == 0);
  const int addrP = p << 2;      // gather: src lane p

  const int blk = blockIdx.x * 4 + wv;   // one 64-point tile per wave
  const int base = blk << 6;
  const float* xp = X + (size_t)(base + lane) * 3;
  float x0 = xp[0], x1 = xp[1], x2 = xp[2];

  // Branch-independent x fragments, stored as 2-word pairs (words 2,3 of the
  // B-frag are always zero; assembled at use).  g>0 lanes hold zeros.
  int xq0[4], xq1[4];
#pragma unroll
  for (int s = 0; s < 4; ++s) {
    int a = (16 * s + p) << 2;
    float fx0 = __int_as_float(__builtin_amdgcn_ds_bpermute(a, __float_as_int(x0)));
    float fx1 = __int_as_float(__builtin_amdgcn_ds_bpermute(a, __float_as_int(x1)));
    float fx2 = __int_as_float(__builtin_amdgcn_ds_bpermute(a, __float_as_int(x2)));
    xq0[s] = g0 ? pkrtz(fx0, fx1) : 0;
    xq1[s] = g0 ? pkrtz(fx2, 1.0f) : 0;
  }

  f4v res4;
#pragma unroll
  for (int b = 0; b < 4; ++b) {
    // Hoisted per-branch weight fragments (w0 kept as 2-word pairs).
    int w0q0[2], w0q1[2];
    h8v w1a[2], w2a[2];
    f4v bs1[2], bs2[2];
#pragma unroll
    for (int t = 0; t < 2; ++t) {
      const int* q = (const int*)&lWT0[b][16 * t + p][0];
      w0q0[t] = g0 ? q[0] : 0;
      w0q1[t] = g0 ? q[1] : 0;
      w1a[t] = *(const h8v*)&lWT1[b][16 * t + p][8 * g];
      w2a[t] = *(const h8v*)&lWT2[b][16 * t + p][8 * g];
      bs1[t] = *(const f4v*)&lB1[b][16 * t + 4 * g];
      bs2[t] = *(const f4v*)&lB2[b][16 * t + 4 * g];
    }
    // L3 A-fragment: W3^T in row 0 (lanes with p==0 hold w3[8g..8g+7]).
    h8v w3z = {0, 0, 0, 0, 0, 0, 0, 0};
    h8v w3a = (p == 0) ? *(const h8v*)&lW3h[b][8 * g] : w3z;
    float b3s = lb3[b];
    float res = 0.0f;

#pragma unroll 2     // half the in-flight chain registers vs full unroll
    for (int s = 0; s < 4; ++s) {
      f4v z = {0.f, 0.f, 0.f, 0.f};
      H8 xs, w0t0, w0t1;
      xs.i[0] = xq0[s];  xs.i[1] = xq1[s];  xs.i[2] = 0;  xs.i[3] = 0;
      w0t0.i[0] = w0q0[0]; w0t0.i[1] = w0q1[0]; w0t0.i[2] = 0; w0t0.i[3] = 0;
      w0t1.i[0] = w0q0[1]; w0t1.i[1] = w0q1[1]; w0t1.i[2] = 0; w0t1.i[3] = 0;
      // L0 (bias folded in k==3 row of W0')
      f4v a0 = __builtin_amdgcn_mfma_f32_16x16x32_f16(w0t0.h, xs.h, z, 0, 0, 0);
      f4v a1 = __builtin_amdgcn_mfma_f32_16x16x32_f16(w0t1.h, xs.h, z, 0, 0, 0);
      H8 hf = make_bfrag(a0, a1);
      // L1
      a0 = __builtin_amdgcn_mfma_f32_16x16x32_f16(w1a[0], hf.h, bs1[0], 0, 0, 0);
      a1 = __builtin_amdgcn_mfma_f32_16x16x32_f16(w1a[1], hf.h, bs1[1], 0, 0, 0);
      hf = make_bfrag(a0, a1);
      // L2
      a0 = __builtin_amdgcn_mfma_f32_16x16x32_f16(w2a[0], hf.h, bs2[0], 0, 0, 0);
      a1 = __builtin_amdgcn_mfma_f32_16x16x32_f16(w2a[1], hf.h, bs2[1], 0, 0, 0);
      hf = make_bfrag(a0, a1);
      // L3: one MFMA; row 0 (reg 0, lanes 0..15) = out[point p]
      f4v o = __builtin_amdgcn_mfma_f32_16x16x32_f16(w3a, hf.h, z, 0, 0, 0);
      // Lane l=16g+p needs subtile g's value for point p (lives in lane p).
      float rr = __int_as_float(__builtin_amdgcn_ds_bpermute(addrP, __float_as_int(o[0])));
      res = (g == s) ? rr : res;
    }
    res4[b] = res + b3s;
  }
  *(f4v*)(Out + (size_t)(base + lane) * 4) = res4;   // one 16B store/point
}

extern "C" void kernel_launch(void* const* d_in, const int* in_sizes, int n_in,
                              void* d_out, int out_size, void* d_ws, size_t ws_size,
                              hipStream_t stream) {
  (void)in_sizes; (void)n_in; (void)out_size; (void)d_ws; (void)ws_size;
  const float* X  = (const float*)d_in[0];
  const float* W0 = (const float*)d_in[1];
  const float* B0 = (const float*)d_in[2];
  const float* W1 = (const float*)d_in[3];
  const float* B1 = (const float*)d_in[4];
  const float* W2 = (const float*)d_in[5];
  const float* B2 = (const float*)d_in[6];
  const float* W3 = (const float*)d_in[7];
  const float* B3 = (const float*)d_in[8];
  float* Out = (float*)d_out;
  pfnn_kernel<<<dim3(GRID_BLOCKS), dim3(BLOCK_THREADS), 0, stream>>>(
      X, W0, B0, W1, B1, W2, B2, W3, B3, Out);
}

// Round 8
// 167.890 us; speedup vs baseline: 2.7074x; 1.0082x over previous
//
#include <hip/hip_runtime.h>
#include <hip/hip_bf16.h>

// PFNN: out[n][b] = L3(tanh(L2(tanh(L1(tanh(L0(x)))))))  B=4, H=32, D_IN=3,
// N=1048576.  f16 MFMA 16x16x32 computing out^T = W^T h^T per 16-pt subtile.
// R7 vs R6 (110us clean, busy-time invariant ~87us across R1/R4/R6 =>
// tanh pipeline is the wall):
//  - exp2 in f16: the y-pair pkrtz doubles as sign source AND exp input;
//    -|y| pair = single v_or(0x80008000).  Kills the e-pack pkrtz, moves
//    trans to v_exp_f16.
//  - deg-3 poly of (1-e)/(1+e) on e in [0,1] (Chebyshev, ripple 2.5e-3;
//    verified at e=0/0.5/1): 3 pk_fma vs 4.
//  - dropped dead g0-selects on xf (B rows k>=4 are don't-care: W0 A-frag
//    zeros those columns).
// Keep: permlane32/16_swap redistribution, bias in MFMA C / W0 k=3 row,
// one 64-pt tile per wave, launch_bounds(256,4), single float4 store.
// Weights/biases of L0..L2 pre-scaled by 2*log2(e) so y is in exp2 domain.

#define NPTS 1048576
constexpr int BLOCK_THREADS = 256;           // 4 waves = 1 wave/SIMD
constexpr int GRID_BLOCKS = NPTS / 64 / 4;   // 4096: one 64-pt tile per wave
constexpr float TANH_SCALE = 2.885390081777927f;  // 2*log2(e)

typedef _Float16 h8v __attribute__((ext_vector_type(8)));
typedef _Float16 h2v __attribute__((ext_vector_type(2)));
typedef float f4v __attribute__((ext_vector_type(4)));
typedef unsigned int u2v __attribute__((ext_vector_type(2)));

union H8 { h8v h; int i[4]; };

extern "C" __device__ _Float16 __ocml_exp2_f16(_Float16);

__device__ __forceinline__ int pkrtz(float a, float b) {
  return __builtin_bit_cast(int, __builtin_amdgcn_cvt_pkrtz(a, b));
}

// Packed tanh of 2 f32 values.  ypk = f16 pair of (y0,y1); e = 2^(-|y|) via
// v_exp_f16 (one v_or builds the negated-abs pair); deg-3 minimax poly of
// (1-e)/(1+e); sign re-inserted from ypk via bfi.
__device__ __forceinline__ int tanh2e(float y0, float y1) {
  int ypk = pkrtz(y0, y1);
  int yn = ypk | 0x80008000;                        // -|y| per half
  h2v yv = __builtin_bit_cast(h2v, yn);
  h2v e;
  e[0] = __ocml_exp2_f16(yv[0]);
  e[1] = __ocml_exp2_f16(yv[1]);
  h2v t = e * (_Float16)-0.4571658f + (_Float16)1.3518220f;
  t = e * t + (_Float16)-1.8937890f;
  t = e * t + (_Float16)0.9970380f;
  int gi = __builtin_bit_cast(int, t);
  return (ypk & 0x80008000) | (gi & 0x7fff7fff);    // copysign (v_bfi)
}

// tanh both accumulator tiles (8 f32), pack, redistribute into next B-frag.
// Quadrant Qi of the wave holds tile0 pairs (A0,A1), tile1 pairs (B0,B1);
// w0=[A0Q0,A0Q2,B0Q0,B0Q2] etc = swap16(swap32(A0,B0)) / swap16(swap32(A1,B1)).
__device__ __forceinline__ H8 make_bfrag(f4v a0, f4v a1) {
  int A0 = tanh2e(a0[0], a0[1]);   // tile0 units (4i,4i+1)
  int A1 = tanh2e(a0[2], a0[3]);   // tile0 units (4i+2,4i+3)
  int B0 = tanh2e(a1[0], a1[1]);   // tile1
  int B1 = tanh2e(a1[2], a1[3]);
  u2v sA = __builtin_amdgcn_permlane32_swap((unsigned)A0, (unsigned)B0, false, false);
  u2v wA = __builtin_amdgcn_permlane16_swap(sA[0], sA[1], false, false);
  u2v sB = __builtin_amdgcn_permlane32_swap((unsigned)A1, (unsigned)B1, false, false);
  u2v wB = __builtin_amdgcn_permlane16_swap(sB[0], sB[1], false, false);
  H8 hf;
  hf.i[0] = (int)wA[0];
  hf.i[1] = (int)wB[0];
  hf.i[2] = (int)wA[1];
  hf.i[3] = (int)wB[1];
  return hf;
}

extern "C" __global__ void __launch_bounds__(BLOCK_THREADS, 4) pfnn_kernel(
    const float* __restrict__ X,
    const float* __restrict__ W0, const float* __restrict__ B0,
    const float* __restrict__ W1, const float* __restrict__ B1,
    const float* __restrict__ W2, const float* __restrict__ B2,
    const float* __restrict__ W3, const float* __restrict__ B3,
    float* __restrict__ Out) {
  __shared__ alignas(16) _Float16 lWT0[4][32][4];    // [b][u][k] k<3: s*W0, k==3: s*b0
  __shared__ alignas(16) _Float16 lWT1[4][32][40];   // [b][u][k], rows padded to 80B
  __shared__ alignas(16) _Float16 lWT2[4][32][40];
  __shared__ alignas(16) float lB1[4][32];           // s*b1 (MFMA C operand)
  __shared__ alignas(16) float lB2[4][32];
  __shared__ alignas(16) _Float16 lW3h[4][32];       // raw W3 (L3 has no tanh)
  __shared__ float lb3[4];

  const int tid = threadIdx.x;
  for (int idx = tid; idx < 512; idx += BLOCK_THREADS) {
    int b = idx >> 7, u = (idx >> 2) & 31, k = idx & 3;
    float v = (k < 3) ? W0[(b * 3 + k) * 32 + u] : B0[b * 32 + u];
    lWT0[b][u][k] = (_Float16)(v * TANH_SCALE);
  }
  for (int idx = tid; idx < 4096; idx += BLOCK_THREADS) {
    int b = idx >> 10, k = (idx >> 5) & 31, u = idx & 31;
    lWT1[b][u][k] = (_Float16)(W1[idx] * TANH_SCALE);
    lWT2[b][u][k] = (_Float16)(W2[idx] * TANH_SCALE);
  }
  for (int idx = tid; idx < 128; idx += BLOCK_THREADS) {
    int b = idx >> 5, u = idx & 31;
    lB1[b][u] = B1[idx] * TANH_SCALE;
    lB2[b][u] = B2[idx] * TANH_SCALE;
    lW3h[b][u] = (_Float16)W3[idx];
  }
  if (tid < 4) lb3[tid] = B3[tid];
  __syncthreads();

  const int lane = tid & 63;
  const int wv = tid >> 6;       // 0..3
  const int g = lane >> 4;       // k-group
  const int p = lane & 15;       // point within subtile
  const bool g0 = (g == 0);
  const int addrP = p << 2;      // gather: src lane p

  const int blk = blockIdx.x * 4 + wv;   // one 64-point tile per wave
  const int base = blk << 6;
  const float* xp = X + (size_t)(base + lane) * 3;
  float x0 = xp[0], x1 = xp[1], x2 = xp[2];

  // Branch-independent x fragments as 2-word pairs.  g>0 lanes hold junk:
  // those B rows are multiplied by the zeroed k>=4 / g>0 columns of the
  // W0 A-fragment, so no select is needed.
  int xq0[4], xq1[4];
#pragma unroll
  for (int s = 0; s < 4; ++s) {
    int a = (16 * s + p) << 2;
    float fx0 = __int_as_float(__builtin_amdgcn_ds_bpermute(a, __float_as_int(x0)));
    float fx1 = __int_as_float(__builtin_amdgcn_ds_bpermute(a, __float_as_int(x1)));
    float fx2 = __int_as_float(__builtin_amdgcn_ds_bpermute(a, __float_as_int(x2)));
    xq0[s] = pkrtz(fx0, fx1);
    xq1[s] = pkrtz(fx2, 1.0f);
  }

  f4v res4;
#pragma unroll
  for (int b = 0; b < 4; ++b) {
    // Hoisted per-branch weight fragments (w0 kept as 2-word pairs).
    int w0q0[2], w0q1[2];
    h8v w1a[2], w2a[2];
    f4v bs1[2], bs2[2];
#pragma unroll
    for (int t = 0; t < 2; ++t) {
      const int* q = (const int*)&lWT0[b][16 * t + p][0];
      w0q0[t] = g0 ? q[0] : 0;
      w0q1[t] = g0 ? q[1] : 0;
      w1a[t] = *(const h8v*)&lWT1[b][16 * t + p][8 * g];
      w2a[t] = *(const h8v*)&lWT2[b][16 * t + p][8 * g];
      bs1[t] = *(const f4v*)&lB1[b][16 * t + 4 * g];
      bs2[t] = *(const f4v*)&lB2[b][16 * t + 4 * g];
    }
    // L3 A-fragment: W3^T in row 0 (lanes with p==0 hold w3[8g..8g+7]).
    h8v w3z = {0, 0, 0, 0, 0, 0, 0, 0};
    h8v w3a = (p == 0) ? *(const h8v*)&lW3h[b][8 * g] : w3z;
    float b3s = lb3[b];
    float res = 0.0f;

#pragma unroll 2     // half the in-flight chain registers vs full unroll
    for (int s = 0; s < 4; ++s) {
      f4v z = {0.f, 0.f, 0.f, 0.f};
      H8 xs, w0t0, w0t1;
      xs.i[0] = xq0[s];  xs.i[1] = xq1[s];  xs.i[2] = 0;  xs.i[3] = 0;
      w0t0.i[0] = w0q0[0]; w0t0.i[1] = w0q1[0]; w0t0.i[2] = 0; w0t0.i[3] = 0;
      w0t1.i[0] = w0q0[1]; w0t1.i[1] = w0q1[1]; w0t1.i[2] = 0; w0t1.i[3] = 0;
      // L0 (bias folded in k==3 row of W0')
      f4v a0 = __builtin_amdgcn_mfma_f32_16x16x32_f16(w0t0.h, xs.h, z, 0, 0, 0);
      f4v a1 = __builtin_amdgcn_mfma_f32_16x16x32_f16(w0t1.h, xs.h, z, 0, 0, 0);
      H8 hf = make_bfrag(a0, a1);
      // L1
      a0 = __builtin_amdgcn_mfma_f32_16x16x32_f16(w1a[0], hf.h, bs1[0], 0, 0, 0);
      a1 = __builtin_amdgcn_mfma_f32_16x16x32_f16(w1a[1], hf.h, bs1[1], 0, 0, 0);
      hf = make_bfrag(a0, a1);
      // L2
      a0 = __builtin_amdgcn_mfma_f32_16x16x32_f16(w2a[0], hf.h, bs2[0], 0, 0, 0);
      a1 = __builtin_amdgcn_mfma_f32_16x16x32_f16(w2a[1], hf.h, bs2[1], 0, 0, 0);
      hf = make_bfrag(a0, a1);
      // L3: one MFMA; row 0 (reg 0, lanes 0..15) = out[point p]
      f4v o = __builtin_amdgcn_mfma_f32_16x16x32_f16(w3a, hf.h, z, 0, 0, 0);
      // Lane l=16g+p needs subtile g's value for point p (lives in lane p).
      float rr = __int_as_float(__builtin_amdgcn_ds_bpermute(addrP, __float_as_int(o[0])));
      res = (g == s) ? rr : res;
    }
    res4[b] = res + b3s;
  }
  *(f4v*)(Out + (size_t)(base + lane) * 4) = res4;   // one 16B store/point
}

extern "C" void kernel_launch(void* const* d_in, const int* in_sizes, int n_in,
                              void* d_out, int out_size, void* d_ws, size_t ws_size,
                              hipStream_t stream) {
  (void)in_sizes; (void)n_in; (void)out_size; (void)d_ws; (void)ws_size;
  const float* X  = (const float*)d_in[0];
  const float* W0 = (const float*)d_in[1];
  const float* B0 = (const float*)d_in[2];
  const float* W1 = (const float*)d_in[3];
  const float* B1 = (const float*)d_in[4];
  const float* W2 = (const float*)d_in[5];
  const float* B2 = (const float*)d_in[6];
  const float* W3 = (const float*)d_in[7];
  const float* B3 = (const float*)d_in[8];
  float* Out = (float*)d_out;
  pfnn_kernel<<<dim3(GRID_BLOCKS), dim3(BLOCK_THREADS), 0, stream>>>(
      X, W0, B0, W1, B1, W2, B2, W3, B3, Out);
}